// Round 10
// baseline (81.326 us; speedup 1.0000x reference)
//
#include <hip/hip_runtime.h>
#include <math.h>

#define KK 49
#define H 128
#define W 128
#define C 64
#define NB 4
#define EPS 1e-7f
#define PLANE (H * W)

#define TW 32              // tile width (pixels)
#define TH 2               // tile height (pixels)
#define HW2 38             // halo width  = TW + 6
#define HH2 8              // halo height = TH + 6
#define NPOS (HW2 * HH2)   // 304 halo positions
#define NP2 (2 * NPOS)     // 608 slots per buffer (2 ch-8-groups of a pass)
#define CADDR (3 * HW2 + 3)// center offset within a thread's window base

// R10 = R8's proven 16-wave/CU structure + PACKED-F16 staging and
// v_dot2_f32_f16 compute. R9's lesson: halving LDS reads at the cost of
// halving occupancy (8 waves/CU) gained ~nothing — the binding constraint is
// waves/CU x per-pass barrier latency. So keep 1024 blocks / 16 waves/CU and
// instead double the channels per ds_read_b128 (8 f16 vs 4 f32) and halve the
// barrier count (CG=16 -> 4 passes). RTZ pack bias (~1e-3 toward zero)
// appears in both the dot and the f16-derived norms -> cancels in the ratio.

typedef _Float16 h2_t __attribute__((ext_vector_type(2)));

__device__ __forceinline__ float fdot2(unsigned int a, unsigned int b, float c) {
    return __builtin_amdgcn_fdot2(__builtin_bit_cast(h2_t, a),
                                  __builtin_bit_cast(h2_t, b), c, false);
}
__device__ __forceinline__ unsigned int packh2(float a, float b) {
    return __builtin_bit_cast(unsigned int, __builtin_amdgcn_cvt_pkrtz(a, b));
}

template<int Q>
__device__ __forceinline__ void compute_q(const uint4* __restrict__ bp,
                                          float (&acc)[13]) {
    constexpr int NK = (Q == 3) ? 13 : 12;
    const uint4 c0 = bp[CADDR];
    const uint4 c1 = bp[NPOS + CADDR];
#pragma unroll
    for (int l = 0; l < NK; ++l) {
        const int k = Q * 12 + l;                    // compile-time after unroll
        const int off = (k / 7) * HW2 + (k % 7);
        const uint4 n0 = bp[off];
        const uint4 n1 = bp[NPOS + off];
        acc[l] = fdot2(c0.x, n0.x, acc[l]);
        acc[l] = fdot2(c0.y, n0.y, acc[l]);
        acc[l] = fdot2(c0.z, n0.z, acc[l]);
        acc[l] = fdot2(c0.w, n0.w, acc[l]);
        acc[l] = fdot2(c1.x, n1.x, acc[l]);
        acc[l] = fdot2(c1.y, n1.y, acc[l]);
        acc[l] = fdot2(c1.z, n1.z, acc[l]);
        acc[l] = fdot2(c1.w, n1.w, acc[l]);
    }
}

template<int Q>
__device__ __forceinline__ void sim_and_max(const float* __restrict__ snb,
                                            float (&acc)[13], float& m) {
    constexpr int NK = (Q == 3) ? 13 : 12;
    const float nc = snb[CADDR];
#pragma unroll
    for (int l = 0; l < NK; ++l) {
        const int k = Q * 12 + l;
        const int off = (k / 7) * HW2 + (k % 7);
        const float nn = snb[off];
        const float sv = __fdividef(acc[l], nc * nn + EPS);
        acc[l] = sv;
        m = fmaxf(m, sv);
    }
}

template<int Q>
__device__ __forceinline__ void exp_and_sum(float (&acc)[13], float m, float& sum) {
    constexpr int NK = (Q == 3) ? 13 : 12;
#pragma unroll
    for (int l = 0; l < NK; ++l) {
        const float e = __expf(acc[l] - m);
        acc[l] = e;
        sum += e;
    }
}

template<int Q>
__device__ __forceinline__ void store_q(float* __restrict__ op,
                                        const float (&acc)[13], float inv) {
    constexpr int NK = (Q == 3) ? 13 : 12;
#pragma unroll
    for (int l = 0; l < NK; ++l)
        op[(size_t)l << 14] = acc[l] * inv;
}

#define DISPATCH_Q(stmt)                                      \
    do {                                                      \
        if (s2 == 0)      { constexpr int Q = 0; stmt; }      \
        else if (s2 == 1) { constexpr int Q = 1; stmt; }      \
        else if (s2 == 2) { constexpr int Q = 2; stmt; }      \
        else              { constexpr int Q = 3; stmt; }      \
    } while (0)

// 256 threads, tile 32x2, FOUR threads per pixel (k-quartered 7x7 window):
//   w = tid&31, r = (tid>>5)&1, s2 = tid>>6 (wave-uniform k-quarter).
// All wave LDS reads/writes and global stores are 32-lane-consecutive 16B/4B
// runs — R2/R5/R7-proven conflict-free (SQ_LDS_BANK_CONFLICT == 0).
// LAUNCH BOUNDS (hard-won): 2nd arg caps VGPRs at 256/arg on this toolchain
// (arg=4 -> 64-reg cap -> 500+MB scratch traffic, R4/R5). arg=2 -> 128 cap.
__global__ __launch_bounds__(256, 2) void rsa_kernel(const float* __restrict__ x,
                                                     float* __restrict__ out) {
    __shared__ uint4 sx[2][NP2];       // 19.0 KB: [buf][grp*NPOS + pos], 8 f16 ch
    __shared__ float sn2[NP2];         // 2.4 KB : per-8-group sum of squares
    __shared__ float snf[NPOS];        // 1.2 KB : final norms
    __shared__ float comb[4][TW * TH]; // 1.0 KB : softmax cross-quarter combine

    const int tid = threadIdx.x;
    const int w   = tid & 31;
    const int r   = (tid >> 5) & 1;
    const int s2  = tid >> 6;          // wave-uniform (wave i -> s2 = i)
    const int w0  = blockIdx.x * TW;
    const int h0  = blockIdx.y * TH;
    const int b   = blockIdx.z;
    const float* __restrict__ xb = x + (size_t)b * C * PLANE;

    // thread's window-origin bases (all window offsets become DS immediates)
    const int roww = r * HW2 + w;
    const uint4* const base4[2] = { &sx[0][0] + roww, &sx[1][0] + roww };

    // ---- staging slot metadata (fixed across passes): slot i = tid + 256*j
    int goff[3], pos[3], hh[3];
    bool act[3], inb[3];
#pragma unroll
    for (int j = 0; j < 3; ++j) {
        int i = tid + j * 256;
        act[j] = (i < NP2);
        int ii = act[j] ? i : 0;
        int g  = (ii >= NPOS) ? 1 : 0;
        int p  = ii - g * NPOS;
        int rr = p / HW2, cc = p - rr * HW2;
        int gh = h0 - 3 + rr, gw = w0 - 3 + cc;
        inb[j]  = (gh >= 0) && (gh < H) && (gw >= 0) && (gw < W);
        goff[j] = gh * W + gw;
        pos[j]  = ii;                  // flat slot index within one buffer
        hh[j]   = g;                   // channel-8-group of the pass
    }

    uint4 pu[3];
    float np[3] = {0.f, 0.f, 0.f};

    auto load_pass = [&](int t) {      // stage 16 channels: 2 groups of 8 (f16)
#pragma unroll
        for (int j = 0; j < 3; ++j) {
            uint4 u = make_uint4(0u, 0u, 0u, 0u);
            if (act[j] && inb[j]) {
                const float* p = xb + (size_t)(t * 16 + hh[j] * 8) * PLANE + goff[j];
                const float f0 = p[0];
                const float f1 = p[PLANE];
                const float f2 = p[2 * PLANE];
                const float f3 = p[3 * PLANE];
                const float f4 = p[4 * PLANE];
                const float f5 = p[5 * PLANE];
                const float f6 = p[6 * PLANE];
                const float f7 = p[7 * PLANE];
                u.x = packh2(f0, f1);
                u.y = packh2(f2, f3);
                u.z = packh2(f4, f5);
                u.w = packh2(f6, f7);
            }
            pu[j] = u;
        }
    };

    auto write_pass = [&](int buf) {
#pragma unroll
        for (int j = 0; j < 3; ++j) {
            if (act[j]) {
                sx[buf][pos[j]] = pu[j];
                // norms from the SAME f16 values as the dot -> RTZ bias cancels
                np[j] = fdot2(pu[j].x, pu[j].x, np[j]);
                np[j] = fdot2(pu[j].y, pu[j].y, np[j]);
                np[j] = fdot2(pu[j].z, pu[j].z, np[j]);
                np[j] = fdot2(pu[j].w, pu[j].w, np[j]);
            }
        }
    };

    float acc[13];
#pragma unroll
    for (int l = 0; l < 13; ++l) acc[l] = 0.f;

    // ---- software-pipelined main loop: 4 passes of 16 channels
    load_pass(0);
    write_pass(0);
    __syncthreads();
#pragma unroll
    for (int t = 0; t < 4; ++t) {
        const int buf = t & 1;
        if (t < 3) load_pass(t + 1);
        DISPATCH_Q(compute_q<Q>(base4[buf], acc));
        if (t < 3) write_pass(buf ^ 1);
        __syncthreads();
    }

    // ---- norms: slot owners hold per-8-group sums over all 4 passes
#pragma unroll
    for (int j = 0; j < 3; ++j)
        if (act[j]) sn2[pos[j]] = np[j];
    __syncthreads();
    for (int i = tid; i < NPOS; i += 256) snf[i] = sqrtf(sn2[i] + sn2[i + NPOS]);
    __syncthreads();

    // ---- cosine sim + cross-quarter softmax
    const float* snb = &snf[0] + roww;
    float m = -1e30f;
    DISPATCH_Q(sim_and_max<Q>(snb, acc, m));

    const int pxi = r * TW + w;
    comb[s2][pxi] = m;
    __syncthreads();
    m = fmaxf(fmaxf(comb[0][pxi], comb[1][pxi]), fmaxf(comb[2][pxi], comb[3][pxi]));
    __syncthreads();

    float sum = 0.f;
    DISPATCH_Q(exp_and_sum<Q>(acc, m, sum));
    comb[s2][pxi] = sum;
    __syncthreads();
    sum = (comb[0][pxi] + comb[1][pxi]) + (comb[2][pxi] + comb[3][pxi]);
    const float inv = __fdividef(1.f, sum);

    float* op = out + (((size_t)b * KK + s2 * 12) << 14) + ((h0 + r) << 7) + (w0 + w);
    DISPATCH_Q(store_q<Q>(op, acc, inv));
}

extern "C" void kernel_launch(void* const* d_in, const int* in_sizes, int n_in,
                              void* d_out, int out_size, void* d_ws, size_t ws_size,
                              hipStream_t stream) {
    const float* x = (const float*)d_in[0];
    float* out = (float*)d_out;

    dim3 block(256, 1, 1);
    dim3 grid(W / TW, H / TH, NB);  // 4 x 64 x 4 = 1024 blocks (4 per CU, 16 waves/CU)
    rsa_kernel<<<grid, block, 0, stream>>>(x, out);
}